// Round 5
// baseline (376.199 us; speedup 1.0000x reference)
//
#include <hip/hip_runtime.h>

// Problem constants (fixed by the reference)
#define NN    100000   // nodes
#define NE    3200000  // edges
#define DIMK  256      // feature dim
#define NC    32       // classes
#define NG    64       // graphs

#define ROWS   128     // nodes per src-bucket
#define NBUCK  782     // ceil(NN/128)
#define CAP    4608    // per-bucket record capacity (mean 4092, sigma ~64 -> +8 sigma)
#define NB1    512     // edge chunks for bucketing (NE/NB1 = 6250 exact)
#define EPB    6250    // edges per bucketing block
#define NSL    16      // reduce slices
#define GRID_F 256     // k_fused blocks (1 per CU; 768 threads = 12 waves)

// Workspace layout (bytes). Total 36.25 MB (round 3 proved ws >= 43.5 MB).
// rec (14.4 MB) overlays deg partials (12.8 MB): parts dead before k_place.
static constexpr size_t OFF_REC    = 0;           // [NBUCK*CAP] u32 = 14,417,920
static constexpr size_t OFF_DEGARR = 14417920;    // [NN] u32
static constexpr size_t OFF_DINV   = 14817920;    // [NN] f32
static constexpr size_t OFF_CNT    = 15217920;    // [NBUCK*NB1] int = 1,601,536
static constexpr size_t OFF_EXC    = 16819456;    // [NBUCK*NB1] int (absolute bases)
static constexpr size_t OFF_BTOT   = 18420992;    // [NBUCK] int (pad 4096)
static constexpr size_t OFF_START  = 18425088;    // [NG+1] int (pad 512)
static constexpr size_t OFF_CTRL   = 18425600;    // int[2]: {i64 flag, work counter} (pad 128)
static constexpr size_t OFF_P2     = 18425728;    // [NSL][NG*DIMK] f32 = 1,048,576
static constexpr size_t OFF_PART   = 19474304;    // [GRID_F][NG*DIMK] f32 = 16,777,216

__device__ __forceinline__ int idx_at(const void* p, long i, bool i64) {
    return i64 ? (int)((const long long*)p)[i] : ((const int*)p)[i];
}

// int64 vs int32 detection (high words of first int64 entries all zero) + zero
// the persistent-block work counter.
__global__ void k_detect(const int* __restrict__ ei_raw, int* __restrict__ ctrl) {
    int z = (ei_raw[1] == 0) + (ei_raw[3] == 0) + (ei_raw[5] == 0) +
            (ei_raw[7] == 0) + (ei_raw[9] == 0) + (ei_raw[11] == 0);
    ctrl[0] = (z == 6) ? 1 : 0;
    ctrl[1] = 0;
}

// Merged edge pass 1.
// Blocks 0..255: degree histogram halves (u8 LDS counters; max deg ~70 << 255).
// Blocks 256..767: per-(bucket,chunk) counts via LDS counters.
__global__ __launch_bounds__(256) void k_pre(const void* __restrict__ ei,
        unsigned int* __restrict__ parts, int* __restrict__ cnt,
        const int* __restrict__ ctrl) {
    __shared__ unsigned int h[12500];   // 50 KB
    const bool i64 = ctrl[0] != 0;
    const int b = blockIdx.x;
    if (b < 256) {
        const int hh = b >> 7;
        const int sl = b & 127;
        const int lo = hh * 50000, hi = lo + 50000;
        for (int t = threadIdx.x; t < 12500; t += 256) h[t] = 0u;
        __syncthreads();
        const int e0 = sl * 25000;
        for (int e = e0 + threadIdx.x; e < e0 + 25000; e += 256) {
            int d = idx_at(ei, (long)NE + e, i64);
            if (d >= lo && d < hi) {
                int r = d - lo;
                atomicAdd(&h[r >> 2], 1u << ((r & 3) * 8));
            }
        }
        __syncthreads();
        for (int t = threadIdx.x; t < 12500; t += 256)
            parts[(size_t)b * 12500 + t] = h[t];
    } else {
        const int k = b - 256;          // 0..511
        for (int t = threadIdx.x; t < NBUCK; t += 256) h[t] = 0u;
        __syncthreads();
        const int e0 = k * EPB;
        for (int e = e0 + threadIdx.x; e < e0 + EPB; e += 256) {
            int s = idx_at(ei, e, i64);
            atomicAdd(&h[s >> 7], 1u);
        }
        __syncthreads();
        for (int t = threadIdx.x; t < NBUCK; t += 256)
            cnt[t * NB1 + k] = (int)h[t];
    }
}

// Merged node/offset pass (512 threads).
// Blocks 0..48: degree reduce -> degarr, dinv.
// Blocks 49..244: graph start offsets from sorted batch.
// Blocks 245..1026: per-bucket exclusive scan of its 512 chunk counts ->
//                   absolute record bases (bkt*CAP + prefix) and bucket totals.
__global__ __launch_bounds__(512) void k_mid(const unsigned int* __restrict__ parts,
        unsigned int* __restrict__ degarr, float* __restrict__ dinv,
        const void* __restrict__ batch, int* __restrict__ start,
        const int* __restrict__ cnt, int* __restrict__ exc, int* __restrict__ btot,
        const int* __restrict__ ctrl) {
    __shared__ int s[512];
    const int b = blockIdx.x;
    const int t = threadIdx.x;
    if (b < 49) {
        int i = b * 512 + t;            // word index 0..24999
        if (i >= 25000) return;
        int h = (i >= 12500) ? 1 : 0;
        int w = i - h * 12500;
        int c0 = 0, c1 = 0, c2 = 0, c3 = 0;
        const unsigned int* base = parts + (size_t)(h * 128) * 12500 + w;
#pragma unroll 4
        for (int q = 0; q < 128; ++q) {
            unsigned int v = base[(size_t)q * 12500];
            c0 += v & 255u; c1 += (v >> 8) & 255u; c2 += (v >> 16) & 255u; c3 += v >> 24;
        }
        int node = h * 50000 + w * 4;
        degarr[node]     = 1u + c0;  dinv[node]     = 1.0f / sqrtf((float)(1 + c0));
        degarr[node + 1] = 1u + c1;  dinv[node + 1] = 1.0f / sqrtf((float)(1 + c1));
        degarr[node + 2] = 1u + c2;  dinv[node + 2] = 1.0f / sqrtf((float)(1 + c2));
        degarr[node + 3] = 1u + c3;  dinv[node + 3] = 1.0f / sqrtf((float)(1 + c3));
    } else if (b < 245) {
        const bool i64 = ctrl[0] != 0;
        int i = (b - 49) * 512 + t;
        if (i >= NN) return;
        int bi = idx_at(batch, i, i64);
        int bp = (i == 0) ? -1 : idx_at(batch, i - 1, i64);
        for (int g = bp + 1; g <= bi; ++g) start[g] = i;
        if (i == NN - 1)
            for (int g = bi + 1; g <= NG; ++g) start[g] = NN;
    } else {
        const int bkt = b - 245;        // 0..781
        int v = cnt[bkt * NB1 + t];
        s[t] = v;
        __syncthreads();
        for (int off = 1; off < 512; off <<= 1) {
            int u = (t >= off) ? s[t - off] : 0;
            __syncthreads();
            s[t] += u;
            __syncthreads();
        }
        exc[bkt * NB1 + t] = bkt * CAP + (s[t] - v);
        if (t == 511) btot[bkt] = s[511];
    }
}

// Place 4-byte edge records: (deg[dst] << 13) | ((src&127)*64 + batch[dst]).
__global__ __launch_bounds__(256) void k_place(const void* __restrict__ ei,
        const void* __restrict__ batch, const unsigned int* __restrict__ degarr,
        const int* __restrict__ exc, unsigned int* __restrict__ rec,
        const int* __restrict__ ctrl) {
    __shared__ unsigned int lc[NBUCK];
    __shared__ int lbase[NBUCK];
    const bool i64 = ctrl[0] != 0;
    const int k = blockIdx.x;
    for (int t = threadIdx.x; t < NBUCK; t += 256) {
        lc[t] = 0u;
        lbase[t] = exc[t * NB1 + k];
    }
    __syncthreads();
    const int e0 = k * EPB;
    for (int e = e0 + threadIdx.x; e < e0 + EPB; e += 256) {
        int s = idx_at(ei, e, i64);
        int d = idx_at(ei, (long)NE + e, i64);
        int g = idx_at(batch, d, i64);
        unsigned int deg = min(degarr[d], 524287u);
        int b = s >> 7;
        unsigned int r = atomicAdd(&lc[b], 1u);
        rec[lbase[b] + (int)r] = (deg << 13) | (unsigned)((s & 127) * 64 + g);
    }
}

// Fused persistent kernel: 768 threads = 3 independent 256-thread units, each
// processing its own bucket; units lockstep through block-wide barriers
// (identical phase shape; empty units keep hitting barriers). 120 KB LDS ->
// 1 block/CU, 12 waves/CU. Work-steal 3 buckets per round via global counter.
__global__ __launch_bounds__(768, 3) void k_fused(
        const float* __restrict__ x, const float* __restrict__ dinv,
        const void* __restrict__ batch, const unsigned int* __restrict__ rec,
        const int* __restrict__ btot, float* __restrict__ part,
        int* __restrict__ ctrl) {
    __shared__ __align__(16) float ldsb[3 * 10240];   // per unit: Ach 8192 + xs 2048
    __shared__ int sbase;
    const bool i64 = ctrl[0] != 0;
    const int tid = threadIdx.x;
    const int u  = tid >> 8;      // unit 0..2
    const int ut = tid & 255;     // thread-in-unit
    const int gi = ut >> 5;       // graph group 0..7
    const int di = ut & 31;       // feature lane
    float* Ach = ldsb + u * 10240;        // [128][64]
    float* xs  = Ach + 8192;              // [8][256]

    float acc[8][8];
#pragma unroll
    for (int g = 0; g < 8; ++g)
#pragma unroll
        for (int k = 0; k < 8; ++k) acc[g][k] = 0.0f;

    const float4* x4 = (const float4*)x;

    for (;;) {
        if (tid == 0) sbase = atomicAdd(&ctrl[1], 3);
        __syncthreads();
        const int base = sbase;
        if (base >= NBUCK) break;
        const int bkt = base + u;
        const bool valid = (bkt < NBUCK);
        const int j0 = bkt * ROWS;
        const int j1 = valid ? min(j0 + ROWS, NN) : j0;

        for (int t = ut; t < 8192; t += 256) Ach[t] = 0.0f;
        __syncthreads();
        if (valid && ut < ROWS) {
            int j = j0 + ut;
            if (j < NN) Ach[ut * 64 + idx_at(batch, j, i64)] = dinv[j];
        }
        __syncthreads();
        const int rb = valid ? bkt * CAP : 0;
        const int re = valid ? rb + btot[bkt] : 0;
        for (int r = rb + ut; r < re; r += 256) {
            unsigned int q = rec[r];
            float val = 1.0f / sqrtf((float)(q >> 13));   // bit-identical to dinv[]
            atomicAdd(&Ach[q & 8191u], val);
        }
        __syncthreads();

        for (int c0 = 0; c0 < ROWS; c0 += 8) {
            // stage 8 x-rows scaled by dinv (zero-pad rows contribute 0)
            for (int t = ut; t < 8 * 64; t += 256) {
                int jj = t >> 6, d4 = t & 63;
                int j = j0 + c0 + jj;
                float4 v = make_float4(0.f, 0.f, 0.f, 0.f);
                if (j < j1) {
                    float dv = dinv[j];
                    float4 w = x4[(size_t)j * 64 + d4];
                    v.x = dv * w.x; v.y = dv * w.y; v.z = dv * w.z; v.w = dv * w.w;
                }
                ((float4*)xs)[jj * 64 + d4] = v;
            }
            __syncthreads();
#pragma unroll
            for (int jj = 0; jj < 8; ++jj) {
                const float* arow = Ach + (c0 + jj) * 64 + gi * 8;
                float4 p0 = *(const float4*)arow;         // broadcast per half-wave
                float4 p1 = *(const float4*)(arow + 4);
                float xv[8];
#pragma unroll
                for (int k = 0; k < 8; ++k) xv[k] = xs[jj * 256 + di + 32 * k];  // bank-free
                float pg[8] = {p0.x, p0.y, p0.z, p0.w, p1.x, p1.y, p1.z, p1.w};
#pragma unroll
                for (int g = 0; g < 8; ++g)
#pragma unroll
                    for (int k = 0; k < 8; ++k)
                        acc[g][k] = fmaf(pg[g], xv[k], acc[g][k]);
            }
            __syncthreads();
        }
    }

    // Combine the 3 units' accumulators in LDS (first 64 KB, now dead), then
    // write one 64 KB block partial. Conflict-free: idx%32 == di.
    __syncthreads();
    if (u == 0) {
#pragma unroll
        for (int g = 0; g < 8; ++g)
#pragma unroll
            for (int k = 0; k < 8; ++k)
                ldsb[(gi * 8 + g) * 256 + k * 32 + di] = acc[g][k];
    }
    __syncthreads();
    if (u == 1) {
#pragma unroll
        for (int g = 0; g < 8; ++g)
#pragma unroll
            for (int k = 0; k < 8; ++k)
                ldsb[(gi * 8 + g) * 256 + k * 32 + di] += acc[g][k];
    }
    __syncthreads();
    if (u == 2) {
#pragma unroll
        for (int g = 0; g < 8; ++g)
#pragma unroll
            for (int k = 0; k < 8; ++k)
                ldsb[(gi * 8 + g) * 256 + k * 32 + di] += acc[g][k];
    }
    __syncthreads();
    float4* p4 = (float4*)(part + (size_t)blockIdx.x * (NG * DIMK));
    for (int t = tid; t < NG * DIMK / 4; t += 768)
        p4[t] = ((const float4*)ldsb)[t];
}

// Split-K reduce stage 1: NSL slices x 4096 float4 cols, coalesced.
__global__ __launch_bounds__(256) void k_reduce1(const float4* __restrict__ part,
        float4* __restrict__ p2) {
    int id = blockIdx.x * 256 + threadIdx.x;   // 0..65535
    int c4 = id & 4095;
    int sl = id >> 12;
    const int span = GRID_F / NSL;             // 16
    int b0 = sl * span;
    float4 s = make_float4(0.f, 0.f, 0.f, 0.f);
#pragma unroll 4
    for (int b = b0; b < b0 + span; ++b) {
        float4 v = part[(size_t)b * 4096 + c4];
        s.x += v.x; s.y += v.y; s.z += v.z; s.w += v.w;
    }
    p2[(size_t)sl * 4096 + c4] = s;
}

// Final: fold NSL slices into S (LDS), then S @ W / cnt + bias.
__global__ __launch_bounds__(256) void k_final(const float* __restrict__ p2,
        const float* __restrict__ W, const float* __restrict__ bias,
        const int* __restrict__ start, float* __restrict__ out) {
    __shared__ float Sb[8 * DIMK];   // 8 KB
    const int tid = threadIdx.x, b = blockIdx.x;
    for (int t = tid; t < 8 * DIMK; t += 256) {
        int gl = t >> 8, d = t & 255;
        float s = 0.f;
#pragma unroll
        for (int sl = 0; sl < NSL; ++sl)
            s += p2[(size_t)sl * (NG * DIMK) + (b * 8 + gl) * DIMK + d];
        Sb[t] = s;
    }
    __syncthreads();
    int g = tid >> 5, c = tid & 31;
    float sum = 0.f;
#pragma unroll 8
    for (int d = 0; d < DIMK; ++d)
        sum = fmaf(Sb[g * DIMK + d], W[d * NC + c], sum);
    int gg = b * 8 + g;
    float cn = (float)max(start[gg + 1] - start[gg], 1);
    out[gg * NC + c] = sum / cn + bias[c];
}

extern "C" void kernel_launch(void* const* d_in, const int* in_sizes, int n_in,
                              void* d_out, int out_size, void* d_ws, size_t ws_size,
                              hipStream_t stream) {
    const float* x    = (const float*)d_in[0];
    const float* W    = (const float*)d_in[1];
    const float* bias = (const float*)d_in[2];
    const void*  ei   = d_in[3];
    const void*  batch= d_in[4];
    float* out = (float*)d_out;

    char* ws = (char*)d_ws;
    unsigned int* rec  = (unsigned int*)(ws + OFF_REC);
    unsigned int* degp = (unsigned int*)(ws + OFF_REC);   // overlay (dead before rec)
    unsigned int* degarr = (unsigned int*)(ws + OFF_DEGARR);
    float* dinv  = (float*)(ws + OFF_DINV);
    int*   cnt   = (int*)(ws + OFF_CNT);
    int*   exc   = (int*)(ws + OFF_EXC);
    int*   btot  = (int*)(ws + OFF_BTOT);
    int*   start = (int*)(ws + OFF_START);
    int*   ctrl  = (int*)(ws + OFF_CTRL);
    float* p2    = (float*)(ws + OFF_P2);
    float* part  = (float*)(ws + OFF_PART);

    k_detect <<<1, 1, 0, stream>>>((const int*)ei, ctrl);
    k_pre    <<<768, 256, 0, stream>>>(ei, degp, cnt, ctrl);
    k_mid    <<<1027, 512, 0, stream>>>(degp, degarr, dinv, batch, start,
                                        cnt, exc, btot, ctrl);
    k_place  <<<NB1, 256, 0, stream>>>(ei, batch, degarr, exc, rec, ctrl);
    k_fused  <<<GRID_F, 768, 0, stream>>>(x, dinv, batch, rec, btot, part, ctrl);
    k_reduce1<<<256, 256, 0, stream>>>((const float4*)part, (float4*)p2);
    k_final  <<<8, 256, 0, stream>>>(p2, W, bias, start, out);
}

// Round 6
// 220.036 us; speedup vs baseline: 1.7097x; 1.7097x over previous
//
#include <hip/hip_runtime.h>

// Problem constants (fixed by the reference)
#define NN    100000   // nodes
#define NE    3200000  // edges
#define DIMK  256      // feature dim
#define NC    32       // classes
#define NG    64       // graphs

#define ROWS   128     // nodes per src-bucket
#define NBUCK  782     // ceil(NN/128)
#define CAP    4608    // per-bucket record capacity (mean 4092, sigma ~64 -> +8 sigma)
#define NB1    512     // edge chunks for bucketing (NE/NB1 = 6250 exact)
#define EPB    6250    // edges per bucketing block
#define NSL    16      // reduce slices
#define MAXG   512     // max k_fused blocks (2/CU)

// Workspace layout (bytes). Fixed region = 15.87 MB; partials sized from ws.
// degarr/cnt/exc overlay the FRONT of the partial region (dead before k_fused).
static constexpr size_t OFF_REC    = 0;           // [NBUCK*CAP] u32 = 14,417,920
                                                  // (first 12.8 MB doubles as deg partials)
static constexpr size_t OFF_DINV   = 14417920;    // [NN] f32 = 400,000
static constexpr size_t OFF_BTOT   = 14817920;    // [NBUCK] int (pad to 3200)
static constexpr size_t OFF_START  = 14821120;    // [NG+1] int (pad 384)
static constexpr size_t OFF_CTRL   = 14821504;    // int[2] (pad 128)
static constexpr size_t OFF_P2     = 14821632;    // [NSL][NG*DIMK] f32 = 1,048,576
static constexpr size_t OFF_PART   = 15870208;    // [grid][NG*DIMK] f32
// overlays (dead before k_fused writes partials):
static constexpr size_t OFF_DEGARR = OFF_PART;              // [NN] u32
static constexpr size_t OFF_CNT    = OFF_PART + 400000;     // [NBUCK*NB1] int
static constexpr size_t OFF_EXC    = OFF_PART + 2001536;    // [NBUCK*NB1] int (ends +3.6MB)

__device__ __forceinline__ int idx_at(const void* p, long i, bool i64) {
    return i64 ? (int)((const long long*)p)[i] : ((const int*)p)[i];
}

// int64 vs int32 detection (high words of first int64 entries all zero) + zero
// the persistent-block work counter.
__global__ void k_detect(const int* __restrict__ ei_raw, int* __restrict__ ctrl) {
    int z = (ei_raw[1] == 0) + (ei_raw[3] == 0) + (ei_raw[5] == 0) +
            (ei_raw[7] == 0) + (ei_raw[9] == 0) + (ei_raw[11] == 0);
    ctrl[0] = (z == 6) ? 1 : 0;
    ctrl[1] = 0;
}

// Merged edge pass 1.
// Blocks 0..255: degree histogram halves (u8 LDS counters; max deg ~70 << 255).
// Blocks 256..767: per-(bucket,chunk) counts via LDS counters.
__global__ __launch_bounds__(256) void k_pre(const void* __restrict__ ei,
        unsigned int* __restrict__ parts, int* __restrict__ cnt,
        const int* __restrict__ ctrl) {
    __shared__ unsigned int h[12500];   // 50 KB
    const bool i64 = ctrl[0] != 0;
    const int b = blockIdx.x;
    if (b < 256) {
        const int hh = b >> 7;
        const int sl = b & 127;
        const int lo = hh * 50000, hi = lo + 50000;
        for (int t = threadIdx.x; t < 12500; t += 256) h[t] = 0u;
        __syncthreads();
        const int e0 = sl * 25000;
        for (int e = e0 + threadIdx.x; e < e0 + 25000; e += 256) {
            int d = idx_at(ei, (long)NE + e, i64);
            if (d >= lo && d < hi) {
                int r = d - lo;
                atomicAdd(&h[r >> 2], 1u << ((r & 3) * 8));
            }
        }
        __syncthreads();
        for (int t = threadIdx.x; t < 12500; t += 256)
            parts[(size_t)b * 12500 + t] = h[t];
    } else {
        const int k = b - 256;          // 0..511
        for (int t = threadIdx.x; t < NBUCK; t += 256) h[t] = 0u;
        __syncthreads();
        const int e0 = k * EPB;
        for (int e = e0 + threadIdx.x; e < e0 + EPB; e += 256) {
            int s = idx_at(ei, e, i64);
            atomicAdd(&h[s >> 7], 1u);
        }
        __syncthreads();
        for (int t = threadIdx.x; t < NBUCK; t += 256)
            cnt[t * NB1 + k] = (int)h[t];
    }
}

// Merged node/offset pass (512 threads).
// Blocks 0..48: degree reduce -> degarr, dinv.
// Blocks 49..244: graph start offsets from sorted batch.
// Blocks 245..1026: per-bucket exclusive scan of its 512 chunk counts ->
//                   absolute record bases (bkt*CAP + prefix) and bucket totals.
__global__ __launch_bounds__(512) void k_mid(const unsigned int* __restrict__ parts,
        unsigned int* __restrict__ degarr, float* __restrict__ dinv,
        const void* __restrict__ batch, int* __restrict__ start,
        const int* __restrict__ cnt, int* __restrict__ exc, int* __restrict__ btot,
        const int* __restrict__ ctrl) {
    __shared__ int s[512];
    const int b = blockIdx.x;
    const int t = threadIdx.x;
    if (b < 49) {
        int i = b * 512 + t;            // word index 0..24999
        if (i >= 25000) return;
        int h = (i >= 12500) ? 1 : 0;
        int w = i - h * 12500;
        int c0 = 0, c1 = 0, c2 = 0, c3 = 0;
        const unsigned int* base = parts + (size_t)(h * 128) * 12500 + w;
#pragma unroll 4
        for (int q = 0; q < 128; ++q) {
            unsigned int v = base[(size_t)q * 12500];
            c0 += v & 255u; c1 += (v >> 8) & 255u; c2 += (v >> 16) & 255u; c3 += v >> 24;
        }
        int node = h * 50000 + w * 4;
        degarr[node]     = 1u + c0;  dinv[node]     = 1.0f / sqrtf((float)(1 + c0));
        degarr[node + 1] = 1u + c1;  dinv[node + 1] = 1.0f / sqrtf((float)(1 + c1));
        degarr[node + 2] = 1u + c2;  dinv[node + 2] = 1.0f / sqrtf((float)(1 + c2));
        degarr[node + 3] = 1u + c3;  dinv[node + 3] = 1.0f / sqrtf((float)(1 + c3));
    } else if (b < 245) {
        const bool i64 = ctrl[0] != 0;
        int i = (b - 49) * 512 + t;
        if (i >= NN) return;
        int bi = idx_at(batch, i, i64);
        int bp = (i == 0) ? -1 : idx_at(batch, i - 1, i64);
        for (int g = bp + 1; g <= bi; ++g) start[g] = i;
        if (i == NN - 1)
            for (int g = bi + 1; g <= NG; ++g) start[g] = NN;
    } else {
        const int bkt = b - 245;        // 0..781
        int v = cnt[bkt * NB1 + t];
        s[t] = v;
        __syncthreads();
        for (int off = 1; off < 512; off <<= 1) {
            int u = (t >= off) ? s[t - off] : 0;
            __syncthreads();
            s[t] += u;
            __syncthreads();
        }
        exc[bkt * NB1 + t] = bkt * CAP + (s[t] - v);
        if (t == 511) btot[bkt] = s[511];
    }
}

// Place 4-byte edge records: (deg[dst] << 13) | ((src&127)*64 + batch[dst]).
__global__ __launch_bounds__(256) void k_place(const void* __restrict__ ei,
        const void* __restrict__ batch, const unsigned int* __restrict__ degarr,
        const int* __restrict__ exc, unsigned int* __restrict__ rec,
        const int* __restrict__ ctrl) {
    __shared__ unsigned int lc[NBUCK];
    __shared__ int lbase[NBUCK];
    const bool i64 = ctrl[0] != 0;
    const int k = blockIdx.x;
    for (int t = threadIdx.x; t < NBUCK; t += 256) {
        lc[t] = 0u;
        lbase[t] = exc[t * NB1 + k];
    }
    __syncthreads();
    const int e0 = k * EPB;
    for (int e = e0 + threadIdx.x; e < e0 + EPB; e += 256) {
        int s = idx_at(ei, e, i64);
        int d = idx_at(ei, (long)NE + e, i64);
        int g = idx_at(batch, d, i64);
        unsigned int deg = min(degarr[d], 524287u);
        int b = s >> 7;
        unsigned int r = atomicAdd(&lc[b], 1u);
        rec[lbase[b] + (int)r] = (deg << 13) | (unsigned)((s & 127) * 64 + g);
    }
}

// Fused persistent kernel, 512 threads, 48 KB LDS, 2 blocks/CU (16 waves/CU).
// Work-steal one bucket at a time. Thread (gi=ut>>6, di=ut&63) accumulates
// acc[8 graphs][4 features] (32 VGPRs - no spill risk). Per row jj: one
// ds_read_b128 for xv, two wave-uniform broadcast b128 for the A-row.
__global__ __launch_bounds__(512, 4) void k_fused(
        const float* __restrict__ x, const float* __restrict__ dinv,
        const void* __restrict__ batch, const unsigned int* __restrict__ rec,
        const int* __restrict__ btot, float* __restrict__ part,
        int* __restrict__ ctrl) {
    __shared__ __align__(16) float Ach[ROWS * 64];   // 32 KB
    __shared__ __align__(16) float xs[16][DIMK];     // 16 KB
    __shared__ int sbkt;
    const bool i64 = ctrl[0] != 0;
    const int tid = threadIdx.x;
    const int gi = tid >> 6;    // graph group 0..7 (wave-uniform)
    const int di = tid & 63;    // feature lane: features di*4..di*4+3

    float acc[8][4];
#pragma unroll
    for (int g = 0; g < 8; ++g)
#pragma unroll
        for (int k = 0; k < 4; ++k) acc[g][k] = 0.0f;

    const float4* x4 = (const float4*)x;

    for (;;) {
        if (tid == 0) sbkt = atomicAdd(&ctrl[1], 1);
        __syncthreads();
        const int bkt = sbkt;
        if (bkt >= NBUCK) break;
        const int j0 = bkt * ROWS;
        const int j1 = min(j0 + ROWS, NN);

        for (int t = tid; t < ROWS * 64; t += 512) Ach[t] = 0.0f;
        __syncthreads();
        if (tid < ROWS) {
            int j = j0 + tid;
            if (j < NN) Ach[tid * 64 + idx_at(batch, j, i64)] = dinv[j];
        }
        __syncthreads();
        const int rb = bkt * CAP;
        const int re = rb + btot[bkt];
        for (int r = rb + tid; r < re; r += 512) {
            unsigned int q = rec[r];
            float val = 1.0f / sqrtf((float)(q >> 13));   // bit-identical to dinv[]
            atomicAdd(&Ach[q & 8191u], val);
        }
        __syncthreads();

        for (int c0 = 0; c0 < ROWS; c0 += 16) {
            // stage 16 x-rows scaled by dinv (zero-pad rows contribute 0)
            for (int t = tid; t < 16 * 64; t += 512) {
                int jj = t >> 6, d4 = t & 63;
                int j = j0 + c0 + jj;
                float4 v = make_float4(0.f, 0.f, 0.f, 0.f);
                if (j < j1) {
                    float dv = dinv[j];
                    float4 w = x4[(size_t)j * 64 + d4];
                    v.x = dv * w.x; v.y = dv * w.y; v.z = dv * w.z; v.w = dv * w.w;
                }
                ((float4*)xs[jj])[d4] = v;
            }
            __syncthreads();
#pragma unroll
            for (int jj = 0; jj < 16; ++jj) {
                const float* arow = Ach + (c0 + jj) * 64 + gi * 8;
                float4 p0 = *(const float4*)arow;         // wave-uniform broadcast
                float4 p1 = *(const float4*)(arow + 4);
                float4 xv = ((const float4*)xs[jj])[di];  // one b128, stride-16B
                float pg[8] = {p0.x, p0.y, p0.z, p0.w, p1.x, p1.y, p1.z, p1.w};
#pragma unroll
                for (int g = 0; g < 8; ++g) {
                    acc[g][0] = fmaf(pg[g], xv.x, acc[g][0]);
                    acc[g][1] = fmaf(pg[g], xv.y, acc[g][1]);
                    acc[g][2] = fmaf(pg[g], xv.z, acc[g][2]);
                    acc[g][3] = fmaf(pg[g], xv.w, acc[g][3]);
                }
            }
            __syncthreads();
        }
    }

    // write block partial (blocks with no work write zeros)
    float* p = part + (size_t)blockIdx.x * (NG * DIMK);
#pragma unroll
    for (int g = 0; g < 8; ++g) {
        float4 w = make_float4(acc[g][0], acc[g][1], acc[g][2], acc[g][3]);
        ((float4*)(p + (gi * 8 + g) * DIMK))[di] = w;
    }
}

// Split-K reduce stage 1: NSL slices x 4096 float4 cols, coalesced.
__global__ __launch_bounds__(256) void k_reduce1(const float4* __restrict__ part,
        float4* __restrict__ p2, int nblk) {
    int id = blockIdx.x * 256 + threadIdx.x;   // 0..65535
    int c4 = id & 4095;
    int sl = id >> 12;
    int span = (nblk + NSL - 1) / NSL;
    int b0 = sl * span, b1 = min(b0 + span, nblk);
    float4 s = make_float4(0.f, 0.f, 0.f, 0.f);
    for (int b = b0; b < b1; ++b) {
        float4 v = part[(size_t)b * 4096 + c4];
        s.x += v.x; s.y += v.y; s.z += v.z; s.w += v.w;
    }
    p2[(size_t)sl * 4096 + c4] = s;
}

// Final: fold NSL slices into S (LDS), then S @ W / cnt + bias.
__global__ __launch_bounds__(256) void k_final(const float* __restrict__ p2,
        const float* __restrict__ W, const float* __restrict__ bias,
        const int* __restrict__ start, float* __restrict__ out) {
    __shared__ float Sb[8 * DIMK];   // 8 KB
    const int tid = threadIdx.x, b = blockIdx.x;
    for (int t = tid; t < 8 * DIMK; t += 256) {
        int gl = t >> 8, d = t & 255;
        float s = 0.f;
#pragma unroll
        for (int sl = 0; sl < NSL; ++sl)
            s += p2[(size_t)sl * (NG * DIMK) + (b * 8 + gl) * DIMK + d];
        Sb[t] = s;
    }
    __syncthreads();
    int g = tid >> 5, c = tid & 31;
    float sum = 0.f;
#pragma unroll 8
    for (int d = 0; d < DIMK; ++d)
        sum = fmaf(Sb[g * DIMK + d], W[d * NC + c], sum);
    int gg = b * 8 + g;
    float cn = (float)max(start[gg + 1] - start[gg], 1);
    out[gg * NC + c] = sum / cn + bias[c];
}

extern "C" void kernel_launch(void* const* d_in, const int* in_sizes, int n_in,
                              void* d_out, int out_size, void* d_ws, size_t ws_size,
                              hipStream_t stream) {
    const float* x    = (const float*)d_in[0];
    const float* W    = (const float*)d_in[1];
    const float* bias = (const float*)d_in[2];
    const void*  ei   = d_in[3];
    const void*  batch= d_in[4];
    float* out = (float*)d_out;

    char* ws = (char*)d_ws;
    unsigned int* rec  = (unsigned int*)(ws + OFF_REC);
    unsigned int* degp = (unsigned int*)(ws + OFF_REC);    // overlay (dead before rec)
    float* dinv  = (float*)(ws + OFF_DINV);
    int*   btot  = (int*)(ws + OFF_BTOT);
    int*   start = (int*)(ws + OFF_START);
    int*   ctrl  = (int*)(ws + OFF_CTRL);
    float* p2    = (float*)(ws + OFF_P2);
    float* part  = (float*)(ws + OFF_PART);
    // overlays inside part region (dead before k_fused writes partials):
    unsigned int* degarr = (unsigned int*)(ws + OFF_DEGARR);
    int*   cnt   = (int*)(ws + OFF_CNT);
    int*   exc   = (int*)(ws + OFF_EXC);

    // grid sized to workspace (known >= ~43.5 MB -> grid >= 421); cap 2/CU.
    long avail = (long)(ws_size - OFF_PART) / 65536;
    int grid = (int)avail;
    if (grid > MAXG) grid = MAXG;
    if (grid < 64) grid = 64;

    k_detect <<<1, 1, 0, stream>>>((const int*)ei, ctrl);
    k_pre    <<<768, 256, 0, stream>>>(ei, degp, cnt, ctrl);
    k_mid    <<<1027, 512, 0, stream>>>(degp, degarr, dinv, batch, start,
                                        cnt, exc, btot, ctrl);
    k_place  <<<NB1, 256, 0, stream>>>(ei, batch, degarr, exc, rec, ctrl);
    k_fused  <<<grid, 512, 0, stream>>>(x, dinv, batch, rec, btot, part, ctrl);
    k_reduce1<<<256, 256, 0, stream>>>((const float4*)part, (float4*)p2, grid);
    k_final  <<<8, 256, 0, stream>>>(p2, W, bias, start, out);
}